// Round 9
// baseline (23.736 us; speedup 1.0000x reference)
//
#include <hip/hip_runtime.h>
#include <math.h>

#define NUM_CLASSES 1000
#define FEAT_DIM    512
#define BATCH       32768
#define LAMDA       0.5f
#define EPS         1e-8f

// Streaming decomposition: TOTAL4 = 2^22 float4s = CB(1024) x SLAB(4096).
// Each block owns a CONTIGUOUS 64KB slab (16 float4/thread, no predication,
// sample-aligned: slab = 32 samples). Centers blocks appended at the end.
#define CB   1024             // streaming center-loss blocks (first)
#define SB   25               // centers-pass blocks (last)
#define GRID (CB + SB)        // 1049 < 2048 -> one residency round
#define ROWS_PER_BLOCK 40     // 25*40 = 1000 center rows
#define TOTAL4  (BATCH * FEAT_DIM / 4)   // 4194304
#define SLAB    4096                      // float4s per streaming block
#define NCHUNK  16                        // SLAB / 256

// ws layout (floats):
//   [0, 25*512)      s partials (per centers-block weighted column sums)
#define DIAG_OFF 25600   // [25600, 25625)  diag partials
#define CL_OFF   26624   // [26624, 26624+CB) center-loss partials

// Two plain kernels; dispatch boundary = cross-XCD visibility (R3-R6 lessons:
// agent fences -> L2 writeback storm ~125us; same-address device atomics
// serialize at ~23ns; completion machinery costs more than a tiny dispatch).

__global__ __launch_bounds__(256, 4) void k_main(const float* __restrict__ feat,
                                                 const float* __restrict__ centers,
                                                 const int* __restrict__ label,
                                                 float* __restrict__ ws) {
    __shared__ float s_sh[4][512];
    __shared__ float d_sh[4];
    __shared__ float sm[4];
    const int t = threadIdx.x;
    const int w = t >> 6, l = t & 63;

    if (blockIdx.x < CB) {
        // ---- center loss: contiguous 64KB slab, 16 chunks, no predication ----
        const float4* f4 = (const float4*)feat;
        const float4* c4 = (const float4*)centers;
        const int base = blockIdx.x * SLAB + t;   // thread's first float4

        int lab[NCHUNK];
#pragma unroll
        for (int k = 0; k < NCHUNK; ++k)
            lab[k] = label[(base + k * 256) >> 7];   // independent, L1-served

        float acc = 0.f;
#pragma unroll
        for (int k = 0; k < NCHUNK; ++k) {
            const int idx = base + k * 256;
            const float4 f = f4[idx];
            const float4 c = c4[lab[k] * 128 + (idx & 127)];
            const float dx = f.x - c.x, dy = f.y - c.y,
                        dz = f.z - c.z, dw = f.w - c.w;
            acc += dx * dx + dy * dy + dz * dz + dw * dw;
        }
        for (int o = 32; o > 0; o >>= 1) acc += __shfl_down(acc, o, 64);
        if (l == 0) sm[w] = acc;
        __syncthreads();
        if (t == 0) ws[CL_OFF + blockIdx.x] = sm[0] + sm[1] + sm[2] + sm[3];
    } else {
        // ---- centers pass: row norms -> inv, s += c*inv, diag += n2*inv^2 ----
        const float4* c4 = (const float4*)centers;
        const int sbid = blockIdx.x - CB;
        const int j0 = sbid * ROWS_PER_BLOCK;
        float4 sa = make_float4(0.f, 0.f, 0.f, 0.f);
        float4 sb = make_float4(0.f, 0.f, 0.f, 0.f);
        float diag = 0.f;
        for (int r = w; r < ROWS_PER_BLOCK; r += 4) {  // 10 rows per wave
            const int j = j0 + r;
            const float4 a = c4[j * 128 + l];
            const float4 b = c4[j * 128 + 64 + l];
            float n2 = a.x*a.x + a.y*a.y + a.z*a.z + a.w*a.w
                     + b.x*b.x + b.y*b.y + b.z*b.z + b.w*b.w;
            for (int o = 32; o > 0; o >>= 1) n2 += __shfl_xor(n2, o, 64);
            const float inv = 1.0f / fmaxf(sqrtf(n2), EPS);
            sa.x += a.x * inv; sa.y += a.y * inv; sa.z += a.z * inv; sa.w += a.w * inv;
            sb.x += b.x * inv; sb.y += b.y * inv; sb.z += b.z * inv; sb.w += b.w * inv;
            diag += n2 * inv * inv;   // identical in all lanes
        }
        s_sh[w][4*l+0] = sa.x; s_sh[w][4*l+1] = sa.y;
        s_sh[w][4*l+2] = sa.z; s_sh[w][4*l+3] = sa.w;
        s_sh[w][256+4*l+0] = sb.x; s_sh[w][256+4*l+1] = sb.y;
        s_sh[w][256+4*l+2] = sb.z; s_sh[w][256+4*l+3] = sb.w;
        if (l == 0) d_sh[w] = diag;
        __syncthreads();
        const float v0 = s_sh[0][t] + s_sh[1][t] + s_sh[2][t] + s_sh[3][t];
        const float v1 = s_sh[0][t+256] + s_sh[1][t+256] + s_sh[2][t+256] + s_sh[3][t+256];
        ws[sbid * 512 + t]       = v0;
        ws[sbid * 512 + 256 + t] = v1;
        if (t == 0)
            ws[DIAG_OFF + sbid] = d_sh[0] + d_sh[1] + d_sh[2] + d_sh[3];
    }
}

// 1 block x 1024 threads: combine everything (all terms linear in partials)
__global__ __launch_bounds__(1024) void k_final(const float* __restrict__ ws,
                                                float* __restrict__ out) {
    __shared__ float sm[16];
    const int t = threadIdx.x;
    const int w = t >> 6, l = t & 63;

    float island = 0.f;
    if (t < 128) {
        // ||s||^2: thread t handles columns 4t..4t+3 as float4
        float4 sq = make_float4(0.f, 0.f, 0.f, 0.f);
#pragma unroll
        for (int bb = 0; bb < SB; ++bb) {
            const float4 p = ((const float4*)(ws + bb * FEAT_DIM))[t];
            sq.x += p.x; sq.y += p.y; sq.z += p.z; sq.w += p.w;
        }
        island = sq.x*sq.x + sq.y*sq.y + sq.z*sq.z + sq.w*sq.w;
    } else if (t < 128 + SB) {
        island = -ws[DIAG_OFF + (t - 128)];          // minus diagonal
    }

    const float cl = ws[CL_OFF + t];                 // CB == 1024 == blockDim
    float val = LAMDA * island + cl * (0.5f / (float)BATCH);

    for (int o = 32; o > 0; o >>= 1) val += __shfl_down(val, o, 64);
    if (l == 0) sm[w] = val;
    __syncthreads();
    if (w == 0) {
        float v = (l < 16) ? sm[l] : 0.f;
        for (int o = 8; o > 0; o >>= 1) v += __shfl_down(v, o, 64);
        if (l == 0)
            out[0] = v + LAMDA * (float)NUM_CLASSES * (float)(NUM_CLASSES - 1);
    }
}

extern "C" void kernel_launch(void* const* d_in, const int* in_sizes, int n_in,
                              void* d_out, int out_size, void* d_ws, size_t ws_size,
                              hipStream_t stream) {
    const int*   label   = (const int*)d_in[0];
    const float* feat    = (const float*)d_in[1];
    const float* centers = (const float*)d_in[2];
    float* ws  = (float*)d_ws;
    float* out = (float*)d_out;

    k_main<<<GRID, 256, 0, stream>>>(feat, centers, label, ws);
    k_final<<<1, 1024, 0, stream>>>(ws, out);
}

// Round 10
// 21.391 us; speedup vs baseline: 1.1096x; 1.1096x over previous
//
#include <hip/hip_runtime.h>
#include <math.h>

#define NUM_CLASSES 1000
#define FEAT_DIM    512
#define BATCH       32768
#define LAMDA       0.5f
#define EPS         1e-8f

// R8 structure (best measured: 21.2us). R9 lesson: centers blocks must come
// FIRST (hidden under streaming pass); grid-strided chunks are already
// device-contiguous per step — contiguous per-block slabs regressed.
#define SB   25               // centers-pass blocks (first, hidden)
#define CB   2023             // streaming center-loss blocks
#define GRID (SB + CB)        // 2048 = 8 blocks/CU x 256 CU, one residency round
#define ROWS_PER_BLOCK 40     // 25*40 = 1000 center rows
#define TOTAL4  (BATCH * FEAT_DIM / 4)   // 4194304 float4s
#define STRIDE  (CB * 256)               // 517888
// chunks 0..7 always in bounds: 517887 + 7*517888 = 4143103 < 4194304
// chunk 8 predicated: only tid < 51200 participates

// ws layout (floats):
//   [0, 25*512)      s partials (per centers-block weighted column sums)
#define DIAG_OFF 25600   // [25600, 25625)  diag partials
#define CL_OFF   26624   // [26624, 26624+CB) center-loss partials

// Two plain kernels; dispatch boundary = cross-XCD visibility (R3-R6 lessons:
// agent fences -> L2 writeback storm ~125us; same-address device atomics
// serialize at ~23ns; completion machinery costs more than a tiny dispatch).

__global__ __launch_bounds__(256, 8) void k_main(const float* __restrict__ feat,
                                                 const float* __restrict__ centers,
                                                 const int* __restrict__ label,
                                                 float* __restrict__ ws) {
    __shared__ float s_sh[4][512];
    __shared__ float d_sh[4];
    __shared__ float sm[4];
    const int t = threadIdx.x;
    const int w = t >> 6, l = t & 63;

    if (blockIdx.x < SB) {
        // ---- centers pass: row norms -> inv, s += c*inv, diag += n2*inv^2 ----
        const float4* c4 = (const float4*)centers;
        const int j0 = blockIdx.x * ROWS_PER_BLOCK;
        float4 sa = make_float4(0.f, 0.f, 0.f, 0.f);
        float4 sb = make_float4(0.f, 0.f, 0.f, 0.f);
        float diag = 0.f;
        for (int r = w; r < ROWS_PER_BLOCK; r += 4) {  // 10 rows per wave
            const int j = j0 + r;
            const float4 a = c4[j * 128 + l];
            const float4 b = c4[j * 128 + 64 + l];
            float n2 = a.x*a.x + a.y*a.y + a.z*a.z + a.w*a.w
                     + b.x*b.x + b.y*b.y + b.z*b.z + b.w*b.w;
            for (int o = 32; o > 0; o >>= 1) n2 += __shfl_xor(n2, o, 64);
            const float inv = 1.0f / fmaxf(sqrtf(n2), EPS);
            sa.x += a.x * inv; sa.y += a.y * inv; sa.z += a.z * inv; sa.w += a.w * inv;
            sb.x += b.x * inv; sb.y += b.y * inv; sb.z += b.z * inv; sb.w += b.w * inv;
            diag += n2 * inv * inv;   // identical in all lanes
        }
        s_sh[w][4*l+0] = sa.x; s_sh[w][4*l+1] = sa.y;
        s_sh[w][4*l+2] = sa.z; s_sh[w][4*l+3] = sa.w;
        s_sh[w][256+4*l+0] = sb.x; s_sh[w][256+4*l+1] = sb.y;
        s_sh[w][256+4*l+2] = sb.z; s_sh[w][256+4*l+3] = sb.w;
        if (l == 0) d_sh[w] = diag;
        __syncthreads();
        const float v0 = s_sh[0][t] + s_sh[1][t] + s_sh[2][t] + s_sh[3][t];
        const float v1 = s_sh[0][t+256] + s_sh[1][t+256] + s_sh[2][t+256] + s_sh[3][t+256];
        ws[blockIdx.x * 512 + t]       = v0;
        ws[blockIdx.x * 512 + 256 + t] = v1;
        if (t == 0)
            ws[DIAG_OFF + blockIdx.x] = d_sh[0] + d_sh[1] + d_sh[2] + d_sh[3];
    } else {
        // ---- center loss: 8 unconditional chunks + 1 predicated ----
        const float4* f4 = (const float4*)feat;
        const float4* c4 = (const float4*)centers;
        const int tid = (blockIdx.x - SB) * 256 + t;

        int lab[9];
#pragma unroll
        for (int k = 0; k < 8; ++k)
            lab[k] = label[(tid + k * STRIDE) >> 7];   // independent loads
        const int idx8 = tid + 8 * STRIDE;
        lab[8] = (idx8 < TOTAL4) ? label[idx8 >> 7] : 0;

        float acc = 0.f;
#pragma unroll
        for (int k = 0; k < 8; ++k) {
            const int idx = tid + k * STRIDE;
            const float4 f = f4[idx];
            const float4 c = c4[lab[k] * 128 + (idx & 127)];
            const float dx = f.x - c.x, dy = f.y - c.y,
                        dz = f.z - c.z, dw = f.w - c.w;
            acc += dx * dx + dy * dy + dz * dz + dw * dw;
        }
        if (idx8 < TOTAL4) {
            const float4 f = f4[idx8];
            const float4 c = c4[lab[8] * 128 + (idx8 & 127)];
            const float dx = f.x - c.x, dy = f.y - c.y,
                        dz = f.z - c.z, dw = f.w - c.w;
            acc += dx * dx + dy * dy + dz * dz + dw * dw;
        }
        for (int o = 32; o > 0; o >>= 1) acc += __shfl_down(acc, o, 64);
        if (l == 0) sm[w] = acc;
        __syncthreads();
        if (t == 0) ws[CL_OFF + (blockIdx.x - SB)] = sm[0] + sm[1] + sm[2] + sm[3];
    }
}

// 1 block x 1024 threads: combine everything (all terms linear in partials)
__global__ __launch_bounds__(1024) void k_final(const float* __restrict__ ws,
                                                float* __restrict__ out) {
    __shared__ float sm[16];
    const int t = threadIdx.x;
    const int w = t >> 6, l = t & 63;

    float island = 0.f;
    if (t < 128) {
        // ||s||^2: thread t handles columns 4t..4t+3 as float4
        float4 sq = make_float4(0.f, 0.f, 0.f, 0.f);
#pragma unroll
        for (int bb = 0; bb < SB; ++bb) {
            const float4 p = ((const float4*)(ws + bb * FEAT_DIM))[t];
            sq.x += p.x; sq.y += p.y; sq.z += p.z; sq.w += p.w;
        }
        island = sq.x*sq.x + sq.y*sq.y + sq.z*sq.z + sq.w*sq.w;
    } else if (t < 128 + SB) {
        island = -ws[DIAG_OFF + (t - 128)];          // minus diagonal
    }

    float cl = (t < CB) ? ws[CL_OFF + t] : 0.f;
    if (t + 1024 < CB) cl += ws[CL_OFF + t + 1024];

    float val = LAMDA * island + cl * (0.5f / (float)BATCH);

    for (int o = 32; o > 0; o >>= 1) val += __shfl_down(val, o, 64);
    if (l == 0) sm[w] = val;
    __syncthreads();
    if (w == 0) {
        float v = (l < 16) ? sm[l] : 0.f;
        for (int o = 8; o > 0; o >>= 1) v += __shfl_down(v, o, 64);
        if (l == 0)
            out[0] = v + LAMDA * (float)NUM_CLASSES * (float)(NUM_CLASSES - 1);
    }
}

extern "C" void kernel_launch(void* const* d_in, const int* in_sizes, int n_in,
                              void* d_out, int out_size, void* d_ws, size_t ws_size,
                              hipStream_t stream) {
    const int*   label   = (const int*)d_in[0];
    const float* feat    = (const float*)d_in[1];
    const float* centers = (const float*)d_in[2];
    float* ws  = (float*)d_ws;
    float* out = (float*)d_out;

    k_main<<<GRID, 256, 0, stream>>>(feat, centers, label, ws);
    k_final<<<1, 1024, 0, stream>>>(ws, out);
}